// Round 1
// baseline (964.739 us; speedup 1.0000x reference)
//
#include <hip/hip_runtime.h>
#include <math.h>

#define C 128
#define B 4096
#define NNODES 500000
#define NOUT 4
#define KTOT 384   // 2C (q_star) + C (h0)

// ---------------------------------------------------------------------------
// ws layout (fp32 elements):
//   h0      [B*C]
//   c0      [B*C]
//   q_star  [B*2C]
//   gates   [B*4C]
//   seg_start [B] (int32)
//   seg_end   [B] (int32)
// total ~16.8 MB
// ---------------------------------------------------------------------------

__global__ void init_state(const float* __restrict__ h, float* __restrict__ h0,
                           float* __restrict__ c0, float* __restrict__ q_star,
                           int* __restrict__ seg_start, int* __restrict__ seg_end) {
    int idx = blockIdx.x * blockDim.x + threadIdx.x;
    if (idx < B * 2 * C) q_star[idx] = 0.f;
    if (idx < B * C) { float t = h[idx]; h0[idx] = t; c0[idx] = t; }
    if (idx < B)     { seg_start[idx] = 0; seg_end[idx] = 0; }
}

__global__ void seg_bounds(const int* __restrict__ batch, int* __restrict__ seg_start,
                           int* __restrict__ seg_end) {
    int n = blockIdx.x * blockDim.x + threadIdx.x;
    if (n >= NNODES) return;
    int b = batch[n];
    if (n == 0 || batch[n - 1] != b) seg_start[b] = n;
    if (n == NNODES - 1 || batch[n + 1] != b) seg_end[b] = n + 1;
}

// ---------------------------------------------------------------------------
// gates[b][j] = sum_k A[b][k] * W[j][k] + b_ih[j] + b_hh[j]
// A = [q_star (256) | h0 (128)], W = [W_ih (512x256) | W_hh (512x128)]
// BM=BN=64, BK=16, 256 threads, 4x4 accum per thread.
// ---------------------------------------------------------------------------
#define BM 64
#define BN 64
#define BK 16
#define LDP 68   // padded LDS leading dim (keeps float4 alignment, breaks pow2 stride)

__global__ __launch_bounds__(256) void lstm_gemm(
    const float* __restrict__ q_star, const float* __restrict__ h0,
    const float* __restrict__ W_ih, const float* __restrict__ W_hh,
    const float* __restrict__ b_ih, const float* __restrict__ b_hh,
    float* __restrict__ gates) {
    __shared__ float As[BK][LDP];
    __shared__ float Bs[BK][LDP];

    const int bm0 = blockIdx.x * BM;
    const int jn0 = blockIdx.y * BN;
    const int tid = threadIdx.x;
    const int tx = tid & 15;       // 0..15 -> 4 output cols each
    const int ty = tid >> 4;       // 0..15 -> 4 output rows each

    // staging: thread loads float4 of A-row (bm0 + tid/4) at k offset (tid%4)*4,
    // same pattern for W-row (jn0 + tid/4)
    const int st_row = tid >> 2;          // 0..63
    const int st_k   = (tid & 3) << 2;    // 0,4,8,12

    float acc[4][4] = {{0.f}};

    for (int k0 = 0; k0 < KTOT; k0 += BK) {
        float4 av, bv;
        {
            const int gb = bm0 + st_row;
            if (k0 < 256)
                av = *(const float4*)(q_star + (size_t)gb * 256 + (k0 + st_k));
            else
                av = *(const float4*)(h0 + (size_t)gb * 128 + (k0 - 256 + st_k));
            const int gj = jn0 + st_row;
            if (k0 < 256)
                bv = *(const float4*)(W_ih + (size_t)gj * 256 + (k0 + st_k));
            else
                bv = *(const float4*)(W_hh + (size_t)gj * 128 + (k0 - 256 + st_k));
        }
        __syncthreads();   // protect LDS from previous iteration's readers
        As[st_k + 0][st_row] = av.x;
        As[st_k + 1][st_row] = av.y;
        As[st_k + 2][st_row] = av.z;
        As[st_k + 3][st_row] = av.w;
        Bs[st_k + 0][st_row] = bv.x;
        Bs[st_k + 1][st_row] = bv.y;
        Bs[st_k + 2][st_row] = bv.z;
        Bs[st_k + 3][st_row] = bv.w;
        __syncthreads();

#pragma unroll
        for (int kk = 0; kk < BK; ++kk) {
            const float4 a4 = *(const float4*)&As[kk][ty << 2];
            const float4 b4 = *(const float4*)&Bs[kk][tx << 2];
            const float a[4] = {a4.x, a4.y, a4.z, a4.w};
            const float bb[4] = {b4.x, b4.y, b4.z, b4.w};
#pragma unroll
            for (int i = 0; i < 4; ++i)
#pragma unroll
                for (int j = 0; j < 4; ++j)
                    acc[i][j] = fmaf(a[i], bb[j], acc[i][j]);
        }
    }

    const int jj = jn0 + (tx << 2);
    const float4 bi = *(const float4*)(b_ih + jj);
    const float4 bh = *(const float4*)(b_hh + jj);
    const float bias[4] = {bi.x + bh.x, bi.y + bh.y, bi.z + bh.z, bi.w + bh.w};
#pragma unroll
    for (int i = 0; i < 4; ++i) {
        const int gb = bm0 + (ty << 2) + i;
        float4 o;
        o.x = acc[i][0] + bias[0];
        o.y = acc[i][1] + bias[1];
        o.z = acc[i][2] + bias[2];
        o.w = acc[i][3] + bias[3];
        *(float4*)(gates + (size_t)gb * (4 * C) + jj) = o;
    }
}

// gate order (i, f, g, o); c = sig(f)*c0 + sig(i)*tanh(g); h = sig(o)*tanh(c)
__global__ void lstm_act(const float* __restrict__ gates, float* __restrict__ c0,
                         float* __restrict__ h0, float* __restrict__ q_star) {
    int idx = blockIdx.x * blockDim.x + threadIdx.x;
    if (idx >= B * C) return;
    int b = idx / C, c = idx % C;
    const float* g = gates + (size_t)b * 4 * C;
    float ii = g[c];
    float ff = g[C + c];
    float gg = g[2 * C + c];
    float oo = g[3 * C + c];
    float si = 1.f / (1.f + __expf(-ii));
    float sf = 1.f / (1.f + __expf(-ff));
    float so = 1.f / (1.f + __expf(-oo));
    float tg = tanhf(gg);
    float cn = sf * c0[idx] + si * tg;
    float hn = so * tanhf(cn);
    c0[idx] = cn;
    h0[idx] = hn;
    q_star[(size_t)b * 2 * C + c] = hn;   // q half of q_star
}

// ---------------------------------------------------------------------------
// Segment attention, one block (4 waves) per segment, online softmax.
// Each wave walks nodes strided by 4; lane holds 2 channels.
// ---------------------------------------------------------------------------
__global__ __launch_bounds__(256) void attention(
    const float* __restrict__ k, const float* __restrict__ v,
    const float* __restrict__ h0, const int* __restrict__ seg_start,
    const int* __restrict__ seg_end, float* __restrict__ q_star,
    float* __restrict__ out, int t) {
    const int b = blockIdx.x;
    const int tid = threadIdx.x;
    const int wave = tid >> 6;
    const int lane = tid & 63;

    __shared__ float q_s[C];
    __shared__ float m_w[4], s_w[4];
    __shared__ float racc[4][C];

    if (tid < C) q_s[tid] = h0[(size_t)b * C + tid];
    __syncthreads();

    const int s0 = seg_start[b];
    const int s1 = seg_end[b];
    const float qa = q_s[lane * 2];
    const float qb = q_s[lane * 2 + 1];

    float m = -INFINITY, ssum = 0.f, acc0 = 0.f, acc1 = 0.f;

    for (int n = s0 + wave; n < s1; n += 4) {
        const float2 kk = *(const float2*)(k + (size_t)n * C + lane * 2);
        float part = kk.x * qa + kk.y * qb;
#pragma unroll
        for (int off = 32; off >= 1; off >>= 1) part += __shfl_xor(part, off);
        const float2 vv = *(const float2*)(v + (size_t)n * C + lane * 2);
        const float mn = fmaxf(m, part);
        const float sc = __expf(m - mn);      // exp(-inf)=0 handles first node
        const float p  = __expf(part - mn);
        ssum = ssum * sc + p;
        acc0 = acc0 * sc + p * vv.x;
        acc1 = acc1 * sc + p * vv.y;
        m = mn;
    }

    if (lane == 0) { m_w[wave] = m; s_w[wave] = ssum; }
    racc[wave][lane * 2]     = acc0;
    racc[wave][lane * 2 + 1] = acc1;
    __syncthreads();

    if (tid < C) {
        const float M = fmaxf(fmaxf(m_w[0], m_w[1]), fmaxf(m_w[2], m_w[3]));
        float S = 0.f, R = 0.f;
#pragma unroll
        for (int w = 0; w < 4; ++w) {
            const float sc = (m_w[w] == -INFINITY) ? 0.f : __expf(m_w[w] - M);
            S = fmaf(s_w[w], sc, S);
            R = fmaf(racc[w][tid], sc, R);
        }
        const float r = R / (S + 1e-16f);
        out[(size_t)b * (NOUT * C) + t * C + tid] = r;
        q_star[(size_t)b * 2 * C + C + tid] = r;   // r half of q_star
    }
}

// ---------------------------------------------------------------------------
extern "C" void kernel_launch(void* const* d_in, const int* in_sizes, int n_in,
                              void* d_out, int out_size, void* d_ws, size_t ws_size,
                              hipStream_t stream) {
    const float* k    = (const float*)d_in[0];
    const float* v    = (const float*)d_in[1];
    const float* h    = (const float*)d_in[2];
    const float* W_ih = (const float*)d_in[3];
    const float* W_hh = (const float*)d_in[4];
    const float* b_ih = (const float*)d_in[5];
    const float* b_hh = (const float*)d_in[6];
    const int*   batch = (const int*)d_in[7];
    float* out = (float*)d_out;

    float* ws      = (float*)d_ws;
    float* h0      = ws;                       // B*C
    float* c0      = h0 + (size_t)B * C;       // B*C
    float* q_star  = c0 + (size_t)B * C;       // B*2C
    float* gates   = q_star + (size_t)B * 2 * C; // B*4C
    int*   sstart  = (int*)(gates + (size_t)B * 4 * C);
    int*   send    = sstart + B;

    init_state<<<(B * 2 * C + 255) / 256, 256, 0, stream>>>(h, h0, c0, q_star, sstart, send);
    seg_bounds<<<(NNODES + 255) / 256, 256, 0, stream>>>(batch, sstart, send);

    for (int t = 0; t < NOUT; ++t) {
        lstm_gemm<<<dim3(B / BM, (4 * C) / BN), 256, 0, stream>>>(
            q_star, h0, W_ih, W_hh, b_ih, b_hh, gates);
        lstm_act<<<(B * C + 255) / 256, 256, 0, stream>>>(gates, c0, h0, q_star);
        attention<<<B, 256, 0, stream>>>(k, v, h0, sstart, send, q_star, out, t);
    }
}

// Round 2
// 957.759 us; speedup vs baseline: 1.0073x; 1.0073x over previous
//
#include <hip/hip_runtime.h>
#include <math.h>

#define C 128
#define B 4096
#define NNODES 500000
#define NOUT 4
#define KTOT 384   // 2C (q_star) + C (h0)

// ---------------------------------------------------------------------------
// ws layout (fp32 elements):
//   h0      [B*C]
//   c0      [B*C]
//   q_star  [B*2C]
//   gates   [B*4C]
//   e_ws    [NNODES]
//   seg_start [B] (int32)
//   seg_end   [B] (int32)
// total ~19 MB
// ---------------------------------------------------------------------------

__global__ void init_state(const float* __restrict__ h, float* __restrict__ h0,
                           float* __restrict__ c0, float* __restrict__ q_star,
                           int* __restrict__ seg_start, int* __restrict__ seg_end) {
    int idx = blockIdx.x * blockDim.x + threadIdx.x;
    if (idx < B * 2 * C) q_star[idx] = 0.f;
    if (idx < B * C) { float t = h[idx]; h0[idx] = t; c0[idx] = t; }
    if (idx < B)     { seg_start[idx] = 0; seg_end[idx] = 0; }
}

__global__ void seg_bounds(const int* __restrict__ batch, int* __restrict__ seg_start,
                           int* __restrict__ seg_end) {
    int n = blockIdx.x * blockDim.x + threadIdx.x;
    if (n >= NNODES) return;
    int b = batch[n];
    if (n == 0 || batch[n - 1] != b) seg_start[b] = n;
    if (n == NNODES - 1 || batch[n + 1] != b) seg_end[b] = n + 1;
}

// ---------------------------------------------------------------------------
// gates[b][j] = sum_k A[b][k] * W[j][k] + b_ih[j] + b_hh[j]
// A = [q_star (256) | h0 (128)], W = [W_ih (512x256) | W_hh (512x128)]
// BM=BN=64, BK=16, 256 threads, 4x4 accum per thread.
// ---------------------------------------------------------------------------
#define BM 64
#define BN 64
#define BK 16
#define LDP 68

__global__ __launch_bounds__(256) void lstm_gemm(
    const float* __restrict__ q_star, const float* __restrict__ h0,
    const float* __restrict__ W_ih, const float* __restrict__ W_hh,
    const float* __restrict__ b_ih, const float* __restrict__ b_hh,
    float* __restrict__ gates) {
    __shared__ float As[BK][LDP];
    __shared__ float Bs[BK][LDP];

    const int bm0 = blockIdx.x * BM;
    const int jn0 = blockIdx.y * BN;
    const int tid = threadIdx.x;
    const int tx = tid & 15;
    const int ty = tid >> 4;

    const int st_row = tid >> 2;
    const int st_k   = (tid & 3) << 2;

    float acc[4][4] = {{0.f}};

    for (int k0 = 0; k0 < KTOT; k0 += BK) {
        float4 av, bv;
        {
            const int gb = bm0 + st_row;
            if (k0 < 256)
                av = *(const float4*)(q_star + (size_t)gb * 256 + (k0 + st_k));
            else
                av = *(const float4*)(h0 + (size_t)gb * 128 + (k0 - 256 + st_k));
            const int gj = jn0 + st_row;
            if (k0 < 256)
                bv = *(const float4*)(W_ih + (size_t)gj * 256 + (k0 + st_k));
            else
                bv = *(const float4*)(W_hh + (size_t)gj * 128 + (k0 - 256 + st_k));
        }
        __syncthreads();
        As[st_k + 0][st_row] = av.x;
        As[st_k + 1][st_row] = av.y;
        As[st_k + 2][st_row] = av.z;
        As[st_k + 3][st_row] = av.w;
        Bs[st_k + 0][st_row] = bv.x;
        Bs[st_k + 1][st_row] = bv.y;
        Bs[st_k + 2][st_row] = bv.z;
        Bs[st_k + 3][st_row] = bv.w;
        __syncthreads();

#pragma unroll
        for (int kk = 0; kk < BK; ++kk) {
            const float4 a4 = *(const float4*)&As[kk][ty << 2];
            const float4 b4 = *(const float4*)&Bs[kk][tx << 2];
            const float a[4] = {a4.x, a4.y, a4.z, a4.w};
            const float bb[4] = {b4.x, b4.y, b4.z, b4.w};
#pragma unroll
            for (int i = 0; i < 4; ++i)
#pragma unroll
                for (int j = 0; j < 4; ++j)
                    acc[i][j] = fmaf(a[i], bb[j], acc[i][j]);
        }
    }

    const int jj = jn0 + (tx << 2);
    const float4 bi = *(const float4*)(b_ih + jj);
    const float4 bh = *(const float4*)(b_hh + jj);
    const float bias[4] = {bi.x + bh.x, bi.y + bh.y, bi.z + bh.z, bi.w + bh.w};
#pragma unroll
    for (int i = 0; i < 4; ++i) {
        const int gb = bm0 + (ty << 2) + i;
        float4 o;
        o.x = acc[i][0] + bias[0];
        o.y = acc[i][1] + bias[1];
        o.z = acc[i][2] + bias[2];
        o.w = acc[i][3] + bias[3];
        *(float4*)(gates + (size_t)gb * (4 * C) + jj) = o;
    }
}

__global__ void lstm_act(const float* __restrict__ gates, float* __restrict__ c0,
                         float* __restrict__ h0, float* __restrict__ q_star) {
    int idx = blockIdx.x * blockDim.x + threadIdx.x;
    if (idx >= B * C) return;
    int b = idx / C, c = idx % C;
    const float* g = gates + (size_t)b * 4 * C;
    float ii = g[c];
    float ff = g[C + c];
    float gg = g[2 * C + c];
    float oo = g[3 * C + c];
    float si = 1.f / (1.f + __expf(-ii));
    float sf = 1.f / (1.f + __expf(-ff));
    float so = 1.f / (1.f + __expf(-oo));
    float tg = tanhf(gg);
    float cn = sf * c0[idx] + si * tg;
    float hn = so * tanhf(cn);
    c0[idx] = cn;
    h0[idx] = hn;
    q_star[(size_t)b * 2 * C + c] = hn;
}

// ---------------------------------------------------------------------------
// Two-phase segment attention. One block (4 waves) per segment.
// Lane layout: group g = lane>>4 (node within 4-node pack), j = lane&15,
// each lane owns channels [j*8, j*8+8). q held in 8 VGPRs.
// P1: e_n = k_n . q  (4 nodes per wave-iter, single 4-step shuffle chain),
//     running max. e_n -> global scratch.
// sum: S = sum exp(e - M) over segment (e L2-hot).
// P2: acc += exp(e-M)*inv_s * v  -- pure streaming, no cross-lane ops.
// ---------------------------------------------------------------------------
__global__ __launch_bounds__(256) void attention(
    const float* __restrict__ k, const float* __restrict__ v,
    const float* __restrict__ h0, const int* __restrict__ seg_start,
    const int* __restrict__ seg_end, float* __restrict__ e_ws,
    float* __restrict__ q_star, float* __restrict__ out, int t) {
    const int b = blockIdx.x;
    const int tid = threadIdx.x;
    const int w = tid >> 6;
    const int lane = tid & 63;
    const int g = lane >> 4;
    const int j = lane & 15;
    const int ch = j << 3;         // 8 channels per lane

    __shared__ float red[4];
    __shared__ float racc[16][C];  // 8 KB partial r

    const int s0 = seg_start[b];
    const int s1 = seg_end[b];

    const float4 qa = *(const float4*)(h0 + (size_t)b * C + ch);
    const float4 qb = *(const float4*)(h0 + (size_t)b * C + ch + 4);

    // ---- P1: scores + running max ----
    float m = -INFINITY;
    for (int n0 = s0 + w * 4; n0 < s1; n0 += 16) {
        const int n = n0 + g;
        if (n < s1) {
            const float4 ka = *(const float4*)(k + (size_t)n * C + ch);
            const float4 kb = *(const float4*)(k + (size_t)n * C + ch + 4);
            float part = ka.x * qa.x + ka.y * qa.y + ka.z * qa.z + ka.w * qa.w
                       + kb.x * qb.x + kb.y * qb.y + kb.z * qb.z + kb.w * qb.w;
            part += __shfl_xor(part, 1);
            part += __shfl_xor(part, 2);
            part += __shfl_xor(part, 4);
            part += __shfl_xor(part, 8);
            if (j == 0) e_ws[n] = part;
            m = fmaxf(m, part);
        }
    }
    m = fmaxf(m, __shfl_xor(m, 16));
    m = fmaxf(m, __shfl_xor(m, 32));
    if (lane == 0) red[w] = m;
    __syncthreads();
    const float M = fmaxf(fmaxf(red[0], red[1]), fmaxf(red[2], red[3]));
    __syncthreads();

    // ---- sum of exp ----
    float s = 0.f;
    for (int n = s0 + tid; n < s1; n += 256) s += __expf(e_ws[n] - M);
#pragma unroll
    for (int off = 32; off >= 1; off >>= 1) s += __shfl_xor(s, off);
    if (lane == 0) red[w] = s;
    __syncthreads();
    const float S = red[0] + red[1] + red[2] + red[3];
    const float inv = 1.f / (S + 1e-16f);

    // ---- P2: weighted v accumulate (streaming) ----
    float4 A0 = {0.f, 0.f, 0.f, 0.f}, A1 = {0.f, 0.f, 0.f, 0.f};
    for (int n0 = s0 + w * 4; n0 < s1; n0 += 16) {
        const int n = n0 + g;
        if (n < s1) {
            const float p = __expf(e_ws[n] - M) * inv;
            const float4 va = *(const float4*)(v + (size_t)n * C + ch);
            const float4 vb = *(const float4*)(v + (size_t)n * C + ch + 4);
            A0.x = fmaf(p, va.x, A0.x); A0.y = fmaf(p, va.y, A0.y);
            A0.z = fmaf(p, va.z, A0.z); A0.w = fmaf(p, va.w, A0.w);
            A1.x = fmaf(p, vb.x, A1.x); A1.y = fmaf(p, vb.y, A1.y);
            A1.z = fmaf(p, vb.z, A1.z); A1.w = fmaf(p, vb.w, A1.w);
        }
    }
    *(float4*)&racc[(w << 2) + g][ch]     = A0;
    *(float4*)&racc[(w << 2) + g][ch + 4] = A1;
    __syncthreads();

    if (tid < C) {
        float r = 0.f;
#pragma unroll
        for (int p = 0; p < 16; ++p) r += racc[p][tid];
        out[(size_t)b * (NOUT * C) + t * C + tid] = r;
        q_star[(size_t)b * 2 * C + C + tid] = r;
    }
}

// ---------------------------------------------------------------------------
extern "C" void kernel_launch(void* const* d_in, const int* in_sizes, int n_in,
                              void* d_out, int out_size, void* d_ws, size_t ws_size,
                              hipStream_t stream) {
    const float* k    = (const float*)d_in[0];
    const float* v    = (const float*)d_in[1];
    const float* h    = (const float*)d_in[2];
    const float* W_ih = (const float*)d_in[3];
    const float* W_hh = (const float*)d_in[4];
    const float* b_ih = (const float*)d_in[5];
    const float* b_hh = (const float*)d_in[6];
    const int*   batch = (const int*)d_in[7];
    float* out = (float*)d_out;

    float* ws      = (float*)d_ws;
    float* h0      = ws;                         // B*C
    float* c0      = h0 + (size_t)B * C;         // B*C
    float* q_star  = c0 + (size_t)B * C;         // B*2C
    float* gates   = q_star + (size_t)B * 2 * C; // B*4C
    float* e_ws    = gates + (size_t)B * 4 * C;  // NNODES
    int*   sstart  = (int*)(e_ws + NNODES);
    int*   send    = sstart + B;

    init_state<<<(B * 2 * C + 255) / 256, 256, 0, stream>>>(h, h0, c0, q_star, sstart, send);
    seg_bounds<<<(NNODES + 255) / 256, 256, 0, stream>>>(batch, sstart, send);

    for (int t = 0; t < NOUT; ++t) {
        lstm_gemm<<<dim3(B / BM, (4 * C) / BN), 256, 0, stream>>>(
            q_star, h0, W_ih, W_hh, b_ih, b_hh, gates);
        lstm_act<<<(B * C + 255) / 256, 256, 0, stream>>>(gates, c0, h0, q_star);
        attention<<<B, 256, 0, stream>>>(k, v, h0, sstart, send, e_ws, q_star, out, t);
    }
}